// Round 5
// baseline (72.956 us; speedup 1.0000x reference)
//
#include <hip/hip_runtime.h>

#define EPS 1e-5f
#define NSLOT 64   // spread-slot copies of the stats accumulators (64 floats each)

__device__ __forceinline__ float waveReduceSum(float v) {
    #pragma unroll
    for (int off = 32; off > 0; off >>= 1)
        v += __shfl_down(v, off, 64);
    return v;
}

// Butterfly-compaction reduction: NV stats spread across lanes.
template <int NV>
__device__ __forceinline__ float statReduce(float (&v)[NV], int lane) {
    #pragma unroll
    for (int b = 0; (1 << b) < NV; ++b) {
        const int d = 1 << b;
        const bool hi = (lane >> b) & 1;
        #pragma unroll
        for (int i = 0; i < (NV >> (b + 1)); ++i) {
            float kept = hi ? v[2 * i + 1] : v[2 * i];
            float sent = hi ? v[2 * i] : v[2 * i + 1];
            float recv = __shfl_xor(sent, d, 64);
            v[i] = kept + recv;
        }
    }
    float r = v[0];
    #pragma unroll
    for (int d = NV; d < 64; d <<= 1)
        r += __shfl_xor(r, d, 64);
    return r;
}

// ---------------- K0: zero the slot accumulators (16 KB) ----------------
// rocclr's fillBufferAligned costs ~40 us/dispatch for this; a 1-block kernel is ~1-2 us.
__global__ __launch_bounds__(256) void k_zero(float4* __restrict__ slots) {
    // NSLOT*64 floats = 1024 float4s; 256 threads x 4 float4
    const float4 z4 = {0.f, 0.f, 0.f, 0.f};
    #pragma unroll
    for (int q = 0; q < 4; ++q)
        slots[q * 256 + threadIdx.x] = z4;
}

// ---------------- K1: sparse conv1 (C=1 -> 8) + per-block BN-stat partials ----------------
__global__ __launch_bounds__(256) void k_conv1(
        const float* __restrict__ f0, const float* __restrict__ W1,
        const float* __restrict__ b1, const int* __restrict__ nbr0,
        float* __restrict__ x1, float* __restrict__ slots, int n0) {
    __shared__ float sred[16];
    int t = threadIdx.x;
    int lane = t & 63;
    if (t < 16) sred[t] = 0.f;
    __syncthreads();

    int n = blockIdx.x * blockDim.x + t;
    bool valid = (n < n0);
    int nn = valid ? n : (n0 - 1);

    int idx[9];
    #pragma unroll
    for (int k = 0; k < 9; ++k) idx[k] = nbr0[(size_t)nn * 9 + k];
    float v[9];
    #pragma unroll
    for (int k = 0; k < 9; ++k) {
        float f = f0[idx[k] >= 0 ? idx[k] : 0];
        v[k] = (idx[k] >= 0) ? f : 0.f;
    }

    // weights via uniform (scalar) loads — no LDS
    float acc[8];
    #pragma unroll
    for (int c = 0; c < 8; ++c) acc[c] = b1[c];
    #pragma unroll
    for (int k = 0; k < 9; ++k)
        #pragma unroll
        for (int c = 0; c < 8; ++c) acc[c] = fmaf(v[k], W1[k * 8 + c], acc[c]);

    if (valid) {
        float4 lo = {acc[0], acc[1], acc[2], acc[3]};
        float4 hi = {acc[4], acc[5], acc[6], acc[7]};
        float4* dst = (float4*)(x1 + (size_t)n * 8);
        dst[0] = lo; dst[1] = hi;
    } else {
        #pragma unroll
        for (int c = 0; c < 8; ++c) acc[c] = 0.f;
    }

    float red[16];
    #pragma unroll
    for (int c = 0; c < 8; ++c) {
        red[c] = acc[c];
        red[8 + c] = acc[c] * acc[c];
    }
    float tot = statReduce<16>(red, lane);
    if (lane < 16) atomicAdd(&sred[lane], tot);
    __syncthreads();
    if (t < 16) {
        float* slot = slots + (size_t)(blockIdx.x & (NSLOT - 1)) * 64;
        atomicAdd(&slot[t], sred[t]);
    }
}

// ---------------- K2: finalize BN1 stats + BN1+ReLU fused into 2x2 max pool ----------------
__global__ __launch_bounds__(256) void k_pool1(
        const float* __restrict__ x1, const int* __restrict__ pmap1,
        const float* __restrict__ slots, const float* __restrict__ gamma1,
        const float* __restrict__ beta1, float* __restrict__ p1,
        int n1, float invn) {
    __shared__ float sstat[16];
    int t = threadIdx.x;
    if (t < 64) {
        const float4* s4 = (const float4*)(slots + (size_t)t * 64);
        float4 a = s4[0], b = s4[1], c4 = s4[2], d = s4[3];
        float vals[16] = {a.x, a.y, a.z, a.w, b.x, b.y, b.z, b.w,
                          c4.x, c4.y, c4.z, c4.w, d.x, d.y, d.z, d.w};
        #pragma unroll
        for (int c = 0; c < 16; ++c) {
            float s = waveReduceSum(vals[c]);
            if (t == 0) sstat[c] = s;
        }
    }
    __syncthreads();

    int i = blockIdx.x * blockDim.x + t;
    if (i >= n1) return;

    float m[8], sc[8], bb[8];
    #pragma unroll
    for (int c = 0; c < 8; ++c) {
        float mu  = sstat[c] * invn;
        float var = sstat[8 + c] * invn - mu * mu;
        m[c]  = mu;
        sc[c] = rsqrtf(var + EPS) * gamma1[c];
        bb[c] = beta1[c];
    }

    int4 pm = ((const int4*)pmap1)[i];
    int idx[4] = {pm.x, pm.y, pm.z, pm.w};
    float best[8];
    #pragma unroll
    for (int c = 0; c < 8; ++c) best[c] = 0.f;  // relu outputs >= 0, >=1 child exists
    #pragma unroll
    for (int k = 0; k < 4; ++k) {
        int j = idx[k] >= 0 ? idx[k] : 0;
        const float4* src = (const float4*)(x1 + (size_t)j * 8);
        float4 lo = src[0], hi = src[1];
        float v[8] = {lo.x, lo.y, lo.z, lo.w, hi.x, hi.y, hi.z, hi.w};
        #pragma unroll
        for (int c = 0; c < 8; ++c) {
            float z = fmaxf(fmaf(v[c] - m[c], sc[c], bb[c]), 0.f);
            z = (idx[k] >= 0) ? z : 0.f;
            best[c] = fmaxf(best[c], z);
        }
    }
    float4 lo = {best[0], best[1], best[2], best[3]};
    float4 hi = {best[4], best[5], best[6], best[7]};
    float4* dst = (float4*)(p1 + (size_t)i * 8);
    dst[0] = lo; dst[1] = hi;
}

// ---------------- K3: sparse conv2 (8 -> 16) + per-block BN-stat partials ----------------
__global__ __launch_bounds__(256, 4) void k_conv2(
        const float* __restrict__ p1, const float* __restrict__ W2,
        const float* __restrict__ b2, const int* __restrict__ nbr1,
        float* __restrict__ x2, float* __restrict__ slots, int n1) {
    __shared__ float sred[32];
    int t = threadIdx.x;
    int lane = t & 63;
    if (t < 32) sred[t] = 0.f;
    __syncthreads();

    int n = blockIdx.x * blockDim.x + t;
    bool valid = (n < n1);
    int nn = valid ? n : (n1 - 1);

    int idx[9];
    #pragma unroll
    for (int k = 0; k < 9; ++k) idx[k] = nbr1[(size_t)nn * 9 + k];

    float acc[16];
    #pragma unroll
    for (int c = 0; c < 16; ++c) acc[c] = b2[c];

    #pragma unroll
    for (int k = 0; k < 9; ++k) {
        const float4* src = (const float4*)(p1 + (size_t)(idx[k] >= 0 ? idx[k] : 0) * 8);
        float4 lo = src[0], hi = src[1];
        if (idx[k] < 0) {
            lo = make_float4(0.f, 0.f, 0.f, 0.f);
            hi = make_float4(0.f, 0.f, 0.f, 0.f);
        }
        float g[8] = {lo.x, lo.y, lo.z, lo.w, hi.x, hi.y, hi.z, hi.w};
        #pragma unroll
        for (int ci = 0; ci < 8; ++ci) {
            #pragma unroll
            for (int c = 0; c < 16; ++c)
                acc[c] = fmaf(g[ci], W2[(k * 8 + ci) * 16 + c], acc[c]);
        }
    }

    if (valid) {
        float4* dst = (float4*)(x2 + (size_t)n * 16);
        #pragma unroll
        for (int q4 = 0; q4 < 4; ++q4) {
            float4 v = {acc[q4 * 4], acc[q4 * 4 + 1], acc[q4 * 4 + 2], acc[q4 * 4 + 3]};
            dst[q4] = v;
        }
    } else {
        #pragma unroll
        for (int c = 0; c < 16; ++c) acc[c] = 0.f;
    }

    float red[32];
    #pragma unroll
    for (int c = 0; c < 16; ++c) {
        red[c] = acc[c];
        red[16 + c] = acc[c] * acc[c];
    }
    float tot = statReduce<32>(red, lane);
    if (lane < 32) atomicAdd(&sred[lane], tot);
    __syncthreads();
    if (t < 32) {
        float* slot = slots + (size_t)(blockIdx.x & (NSLOT - 1)) * 64;
        atomicAdd(&slot[16 + t], sred[t]);
    }
}

// ---------------- K4: finalize BN2 stats + BN2+ReLU fused into pool + FC(16->2) ----------------
__global__ __launch_bounds__(256) void k_pool2_fc(
        const float* __restrict__ x2, const int* __restrict__ pmap2,
        const float* __restrict__ slots, const float* __restrict__ gamma2,
        const float* __restrict__ beta2, const float* __restrict__ Wfc,
        const float* __restrict__ bfc, float* __restrict__ out,
        int n2, float invn) {
    __shared__ float sstat[32];
    int t = threadIdx.x;
    if (t < 64) {
        const float4* s4 = (const float4*)(slots + (size_t)t * 64 + 16);
        float vals[32];
        #pragma unroll
        for (int q = 0; q < 8; ++q) {
            float4 a = s4[q];
            vals[q * 4 + 0] = a.x; vals[q * 4 + 1] = a.y;
            vals[q * 4 + 2] = a.z; vals[q * 4 + 3] = a.w;
        }
        #pragma unroll
        for (int c = 0; c < 32; ++c) {
            float s = waveReduceSum(vals[c]);
            if (t == 0) sstat[c] = s;
        }
    }
    __syncthreads();

    int i = blockIdx.x * blockDim.x + t;
    if (i >= n2) return;

    float m[16], sc[16], bb[16];
    #pragma unroll
    for (int c = 0; c < 16; ++c) {
        float mu  = sstat[c] * invn;
        float var = sstat[16 + c] * invn - mu * mu;
        m[c]  = mu;
        sc[c] = rsqrtf(var + EPS) * gamma2[c];
        bb[c] = beta2[c];
    }

    int4 pm = ((const int4*)pmap2)[i];
    int idx[4] = {pm.x, pm.y, pm.z, pm.w};
    float best[16];
    #pragma unroll
    for (int c = 0; c < 16; ++c) best[c] = 0.f;
    #pragma unroll
    for (int k = 0; k < 4; ++k) {
        int j = idx[k] >= 0 ? idx[k] : 0;
        const float4* src = (const float4*)(x2 + (size_t)j * 16);
        #pragma unroll
        for (int q4 = 0; q4 < 4; ++q4) {
            float4 v4 = src[q4];
            float v[4] = {v4.x, v4.y, v4.z, v4.w};
            #pragma unroll
            for (int c = 0; c < 4; ++c) {
                int cc = q4 * 4 + c;
                float z = fmaxf(fmaf(v[c] - m[cc], sc[cc], bb[cc]), 0.f);
                z = (idx[k] >= 0) ? z : 0.f;
                best[cc] = fmaxf(best[cc], z);
            }
        }
    }
    float o0 = bfc[0], o1 = bfc[1];
    #pragma unroll
    for (int c = 0; c < 16; ++c) {
        o0 = fmaf(best[c], Wfc[c * 2 + 0], o0);
        o1 = fmaf(best[c], Wfc[c * 2 + 1], o1);
    }
    out[(size_t)i * 2 + 0] = o0;
    out[(size_t)i * 2 + 1] = o1;
}

extern "C" void kernel_launch(void* const* d_in, const int* in_sizes, int n_in,
                              void* d_out, int out_size, void* d_ws, size_t ws_size,
                              hipStream_t stream) {
    const float* f0     = (const float*)d_in[0];
    const float* W1     = (const float*)d_in[1];
    const float* b1     = (const float*)d_in[2];
    const float* gamma1 = (const float*)d_in[3];
    const float* beta1  = (const float*)d_in[4];
    const float* W2     = (const float*)d_in[5];
    const float* b2     = (const float*)d_in[6];
    const float* gamma2 = (const float*)d_in[7];
    const float* beta2  = (const float*)d_in[8];
    const float* Wfc    = (const float*)d_in[9];
    const float* bfc    = (const float*)d_in[10];
    const int*   nbr0   = (const int*)d_in[11];
    const int*   pmap1  = (const int*)d_in[12];
    const int*   nbr1   = (const int*)d_in[13];
    const int*   pmap2  = (const int*)d_in[14];

    const int n0 = in_sizes[0];
    const int n1 = in_sizes[12] / 4;
    const int n2 = in_sizes[14] / 4;

    float* ws    = (float*)d_ws;
    float* slots = ws;                              // NSLOT * 64 floats
    float* x1    = ws + (size_t)NSLOT * 64;         // n0*8
    float* p1    = x1 + (size_t)n0 * 8;             // n1*8
    float* x2    = p1 + (size_t)n1 * 8;             // n1*16

    const int B = 256;
    k_zero<<<1, B, 0, stream>>>((float4*)slots);
    k_conv1<<<(n0 + B - 1) / B, B, 0, stream>>>(f0, W1, b1, nbr0, x1, slots, n0);
    k_pool1<<<(n1 + B - 1) / B, B, 0, stream>>>(x1, pmap1, slots, gamma1, beta1, p1,
                                                n1, 1.0f / (float)n0);
    k_conv2<<<(n1 + B - 1) / B, B, 0, stream>>>(p1, W2, b2, nbr1, x2, slots, n1);
    k_pool2_fc<<<(n2 + B - 1) / B, B, 0, stream>>>(x2, pmap2, slots, gamma2, beta2,
                                                   Wfc, bfc, (float*)d_out,
                                                   n2, 1.0f / (float)n1);
}

// Round 6
// 70.649 us; speedup vs baseline: 1.0327x; 1.0327x over previous
//
#include <hip/hip_runtime.h>

#define EPS 1e-5f
#define NSLOT 64   // spread-slot copies of the stats accumulators (64 floats each)

__device__ __forceinline__ float waveReduceSum(float v) {
    #pragma unroll
    for (int off = 32; off > 0; off >>= 1)
        v += __shfl_down(v, off, 64);
    return v;
}

// Butterfly-compaction reduction: NV stats spread across lanes.
template <int NV>
__device__ __forceinline__ float statReduce(float (&v)[NV], int lane) {
    #pragma unroll
    for (int b = 0; (1 << b) < NV; ++b) {
        const int d = 1 << b;
        const bool hi = (lane >> b) & 1;
        #pragma unroll
        for (int i = 0; i < (NV >> (b + 1)); ++i) {
            float kept = hi ? v[2 * i + 1] : v[2 * i];
            float sent = hi ? v[2 * i] : v[2 * i + 1];
            float recv = __shfl_xor(sent, d, 64);
            v[i] = kept + recv;
        }
    }
    float r = v[0];
    #pragma unroll
    for (int d = NV; d < 64; d <<= 1)
        r += __shfl_xor(r, d, 64);
    return r;
}

// ---------------- K0: zero the slot accumulators (16 KB) ----------------
__global__ __launch_bounds__(256) void k_zero(float4* __restrict__ slots) {
    const float4 z4 = {0.f, 0.f, 0.f, 0.f};
    #pragma unroll
    for (int q = 0; q < 4; ++q)
        slots[q * 256 + threadIdx.x] = z4;
}

// ---------------- K1: sparse conv1 (C=1 -> 8) + per-block BN-stat partials ----------------
__global__ __launch_bounds__(256) void k_conv1(
        const float* __restrict__ f0, const float* __restrict__ W1,
        const float* __restrict__ b1, const int* __restrict__ nbr0,
        float* __restrict__ x1, float* __restrict__ slots, int n0) {
    __shared__ float sred[16];
    int t = threadIdx.x;
    int lane = t & 63;
    if (t < 16) sred[t] = 0.f;
    __syncthreads();

    int n = blockIdx.x * blockDim.x + t;
    bool valid = (n < n0);
    int nn = valid ? n : (n0 - 1);

    int idx[9];
    #pragma unroll
    for (int k = 0; k < 9; ++k) idx[k] = nbr0[(size_t)nn * 9 + k];
    float v[9];
    #pragma unroll
    for (int k = 0; k < 9; ++k) {
        float f = f0[idx[k] >= 0 ? idx[k] : 0];
        v[k] = (idx[k] >= 0) ? f : 0.f;
    }

    // weights via uniform (scalar) loads — no LDS
    float acc[8];
    #pragma unroll
    for (int c = 0; c < 8; ++c) acc[c] = b1[c];
    #pragma unroll
    for (int k = 0; k < 9; ++k)
        #pragma unroll
        for (int c = 0; c < 8; ++c) acc[c] = fmaf(v[k], W1[k * 8 + c], acc[c]);

    if (valid) {
        float4 lo = {acc[0], acc[1], acc[2], acc[3]};
        float4 hi = {acc[4], acc[5], acc[6], acc[7]};
        float4* dst = (float4*)(x1 + (size_t)n * 8);
        dst[0] = lo; dst[1] = hi;
    } else {
        #pragma unroll
        for (int c = 0; c < 8; ++c) acc[c] = 0.f;
    }

    float red[16];
    #pragma unroll
    for (int c = 0; c < 8; ++c) {
        red[c] = acc[c];
        red[8 + c] = acc[c] * acc[c];
    }
    float tot = statReduce<16>(red, lane);
    if (lane < 16) atomicAdd(&sred[lane], tot);
    __syncthreads();
    if (t < 16) {
        float* slot = slots + (size_t)(blockIdx.x & (NSLOT - 1)) * 64;
        atomicAdd(&slot[t], sred[t]);
    }
}

// ---------------- K2: finalize BN1 stats + BN1+ReLU fused into 2x2 max pool ----------------
__global__ __launch_bounds__(256) void k_pool1(
        const float* __restrict__ x1, const int* __restrict__ pmap1,
        const float* __restrict__ slots, const float* __restrict__ gamma1,
        const float* __restrict__ beta1, float* __restrict__ p1,
        int n1, float invn) {
    __shared__ float sstat[16];
    int t = threadIdx.x;
    if (t < 64) {
        const float4* s4 = (const float4*)(slots + (size_t)t * 64);
        float4 a = s4[0], b = s4[1], c4 = s4[2], d = s4[3];
        float vals[16] = {a.x, a.y, a.z, a.w, b.x, b.y, b.z, b.w,
                          c4.x, c4.y, c4.z, c4.w, d.x, d.y, d.z, d.w};
        #pragma unroll
        for (int c = 0; c < 16; ++c) {
            float s = waveReduceSum(vals[c]);
            if (t == 0) sstat[c] = s;
        }
    }
    __syncthreads();

    int i = blockIdx.x * blockDim.x + t;
    if (i >= n1) return;

    float m[8], sc[8], bb[8];
    #pragma unroll
    for (int c = 0; c < 8; ++c) {
        float mu  = sstat[c] * invn;
        float var = sstat[8 + c] * invn - mu * mu;
        m[c]  = mu;
        sc[c] = rsqrtf(var + EPS) * gamma1[c];
        bb[c] = beta1[c];
    }

    int4 pm = ((const int4*)pmap1)[i];
    int idx[4] = {pm.x, pm.y, pm.z, pm.w};
    float best[8];
    #pragma unroll
    for (int c = 0; c < 8; ++c) best[c] = 0.f;  // relu outputs >= 0, >=1 child exists
    #pragma unroll
    for (int k = 0; k < 4; ++k) {
        int j = idx[k] >= 0 ? idx[k] : 0;
        const float4* src = (const float4*)(x1 + (size_t)j * 8);
        float4 lo = src[0], hi = src[1];
        float v[8] = {lo.x, lo.y, lo.z, lo.w, hi.x, hi.y, hi.z, hi.w};
        #pragma unroll
        for (int c = 0; c < 8; ++c) {
            float z = fmaxf(fmaf(v[c] - m[c], sc[c], bb[c]), 0.f);
            z = (idx[k] >= 0) ? z : 0.f;
            best[c] = fmaxf(best[c], z);
        }
    }
    float4 lo = {best[0], best[1], best[2], best[3]};
    float4 hi = {best[4], best[5], best[6], best[7]};
    float4* dst = (float4*)(p1 + (size_t)i * 8);
    dst[0] = lo; dst[1] = hi;
}

// ---------------- K3: sparse conv2 (8 -> 16) + per-block BN-stat partials ----------------
// launch_bounds(256,6): cap ~85 VGPR -> 6 waves/SIMD (was 4). More TLP to hide the
// idx->gather dependent chain; compiler keeps ~2 taps in flight within the budget.
__global__ __launch_bounds__(256, 6) void k_conv2(
        const float* __restrict__ p1, const float* __restrict__ W2,
        const float* __restrict__ b2, const int* __restrict__ nbr1,
        float* __restrict__ x2, float* __restrict__ slots, int n1) {
    __shared__ float sred[32];
    int t = threadIdx.x;
    int lane = t & 63;
    if (t < 32) sred[t] = 0.f;
    __syncthreads();

    int n = blockIdx.x * blockDim.x + t;
    bool valid = (n < n1);
    int nn = valid ? n : (n1 - 1);

    int idx[9];
    #pragma unroll
    for (int k = 0; k < 9; ++k) idx[k] = nbr1[(size_t)nn * 9 + k];

    float acc[16];
    #pragma unroll
    for (int c = 0; c < 16; ++c) acc[c] = b2[c];

    #pragma unroll
    for (int k = 0; k < 9; ++k) {
        const float4* src = (const float4*)(p1 + (size_t)(idx[k] >= 0 ? idx[k] : 0) * 8);
        float4 lo = src[0], hi = src[1];
        if (idx[k] < 0) {
            lo = make_float4(0.f, 0.f, 0.f, 0.f);
            hi = make_float4(0.f, 0.f, 0.f, 0.f);
        }
        float g[8] = {lo.x, lo.y, lo.z, lo.w, hi.x, hi.y, hi.z, hi.w};
        #pragma unroll
        for (int ci = 0; ci < 8; ++ci) {
            #pragma unroll
            for (int c = 0; c < 16; ++c)
                acc[c] = fmaf(g[ci], W2[(k * 8 + ci) * 16 + c], acc[c]);
        }
    }

    if (valid) {
        float4* dst = (float4*)(x2 + (size_t)n * 16);
        #pragma unroll
        for (int q4 = 0; q4 < 4; ++q4) {
            float4 v = {acc[q4 * 4], acc[q4 * 4 + 1], acc[q4 * 4 + 2], acc[q4 * 4 + 3]};
            dst[q4] = v;
        }
    } else {
        #pragma unroll
        for (int c = 0; c < 16; ++c) acc[c] = 0.f;
    }

    float red[32];
    #pragma unroll
    for (int c = 0; c < 16; ++c) {
        red[c] = acc[c];
        red[16 + c] = acc[c] * acc[c];
    }
    float tot = statReduce<32>(red, lane);
    if (lane < 32) atomicAdd(&sred[lane], tot);
    __syncthreads();
    if (t < 32) {
        float* slot = slots + (size_t)(blockIdx.x & (NSLOT - 1)) * 64;
        atomicAdd(&slot[16 + t], sred[t]);
    }
}

// ---------------- K4: finalize BN2 stats + BN2+ReLU fused into pool + FC(16->2) ----------------
__global__ __launch_bounds__(256) void k_pool2_fc(
        const float* __restrict__ x2, const int* __restrict__ pmap2,
        const float* __restrict__ slots, const float* __restrict__ gamma2,
        const float* __restrict__ beta2, const float* __restrict__ Wfc,
        const float* __restrict__ bfc, float* __restrict__ out,
        int n2, float invn) {
    __shared__ float sstat[32];
    int t = threadIdx.x;
    if (t < 64) {
        const float4* s4 = (const float4*)(slots + (size_t)t * 64 + 16);
        float vals[32];
        #pragma unroll
        for (int q = 0; q < 8; ++q) {
            float4 a = s4[q];
            vals[q * 4 + 0] = a.x; vals[q * 4 + 1] = a.y;
            vals[q * 4 + 2] = a.z; vals[q * 4 + 3] = a.w;
        }
        #pragma unroll
        for (int c = 0; c < 32; ++c) {
            float s = waveReduceSum(vals[c]);
            if (t == 0) sstat[c] = s;
        }
    }
    __syncthreads();

    int i = blockIdx.x * blockDim.x + t;
    if (i >= n2) return;

    float m[16], sc[16], bb[16];
    #pragma unroll
    for (int c = 0; c < 16; ++c) {
        float mu  = sstat[c] * invn;
        float var = sstat[16 + c] * invn - mu * mu;
        m[c]  = mu;
        sc[c] = rsqrtf(var + EPS) * gamma2[c];
        bb[c] = beta2[c];
    }

    int4 pm = ((const int4*)pmap2)[i];
    int idx[4] = {pm.x, pm.y, pm.z, pm.w};
    float best[16];
    #pragma unroll
    for (int c = 0; c < 16; ++c) best[c] = 0.f;
    #pragma unroll
    for (int k = 0; k < 4; ++k) {
        int j = idx[k] >= 0 ? idx[k] : 0;
        const float4* src = (const float4*)(x2 + (size_t)j * 16);
        #pragma unroll
        for (int q4 = 0; q4 < 4; ++q4) {
            float4 v4 = src[q4];
            float v[4] = {v4.x, v4.y, v4.z, v4.w};
            #pragma unroll
            for (int c = 0; c < 4; ++c) {
                int cc = q4 * 4 + c;
                float z = fmaxf(fmaf(v[c] - m[cc], sc[cc], bb[cc]), 0.f);
                z = (idx[k] >= 0) ? z : 0.f;
                best[cc] = fmaxf(best[cc], z);
            }
        }
    }
    float o0 = bfc[0], o1 = bfc[1];
    #pragma unroll
    for (int c = 0; c < 16; ++c) {
        o0 = fmaf(best[c], Wfc[c * 2 + 0], o0);
        o1 = fmaf(best[c], Wfc[c * 2 + 1], o1);
    }
    out[(size_t)i * 2 + 0] = o0;
    out[(size_t)i * 2 + 1] = o1;
}

extern "C" void kernel_launch(void* const* d_in, const int* in_sizes, int n_in,
                              void* d_out, int out_size, void* d_ws, size_t ws_size,
                              hipStream_t stream) {
    const float* f0     = (const float*)d_in[0];
    const float* W1     = (const float*)d_in[1];
    const float* b1     = (const float*)d_in[2];
    const float* gamma1 = (const float*)d_in[3];
    const float* beta1  = (const float*)d_in[4];
    const float* W2     = (const float*)d_in[5];
    const float* b2     = (const float*)d_in[6];
    const float* gamma2 = (const float*)d_in[7];
    const float* beta2  = (const float*)d_in[8];
    const float* Wfc    = (const float*)d_in[9];
    const float* bfc    = (const float*)d_in[10];
    const int*   nbr0   = (const int*)d_in[11];
    const int*   pmap1  = (const int*)d_in[12];
    const int*   nbr1   = (const int*)d_in[13];
    const int*   pmap2  = (const int*)d_in[14];

    const int n0 = in_sizes[0];
    const int n1 = in_sizes[12] / 4;
    const int n2 = in_sizes[14] / 4;

    float* ws    = (float*)d_ws;
    float* slots = ws;                              // NSLOT * 64 floats
    float* x1    = ws + (size_t)NSLOT * 64;         // n0*8
    float* p1    = x1 + (size_t)n0 * 8;             // n1*8
    float* x2    = p1 + (size_t)n1 * 8;             // n1*16

    const int B = 256;
    k_zero<<<1, B, 0, stream>>>((float4*)slots);
    k_conv1<<<(n0 + B - 1) / B, B, 0, stream>>>(f0, W1, b1, nbr0, x1, slots, n0);
    k_pool1<<<(n1 + B - 1) / B, B, 0, stream>>>(x1, pmap1, slots, gamma1, beta1, p1,
                                                n1, 1.0f / (float)n0);
    k_conv2<<<(n1 + B - 1) / B, B, 0, stream>>>(p1, W2, b2, nbr1, x2, slots, n1);
    k_pool2_fc<<<(n2 + B - 1) / B, B, 0, stream>>>(x2, pmap2, slots, gamma2, beta2,
                                                   Wfc, bfc, (float*)d_out,
                                                   n2, 1.0f / (float)n1);
}